// Round 8
// baseline (94.565 us; speedup 1.0000x reference)
//
#include <hip/hip_runtime.h>
#include <stdint.h>

#define NC 14
#define DIM 96
#define VOL (96 * 96 * 96)     // 884736
#define TPB 256
#define NBPB (VOL / TPB)       // 3456 blocks per batch
#define NSLAB (2 * NC)         // 28 slabs (14 S + 14 T), 1 KB each

typedef __attribute__((address_space(3))) void as3_void;
typedef const __attribute__((address_space(1))) void as1_cvoid;

__global__ __launch_bounds__(256) void bkd_main(const float* __restrict__ S,
                                                const float* __restrict__ T,
                                                const int* __restrict__ L,
                                                float* __restrict__ partials) {
    __shared__ float smem[NSLAB * TPB];        // 28 KB class-slab staging
    __shared__ float lds_sum[4][NC];
    __shared__ float lds_cnt[4][NC];

    const int blk = blockIdx.x;
    const int b = blk / NBPB;
    const int local = blk % NBPB;
    const int tid = threadIdx.x;
    const int lane = tid & 63, wid = tid >> 6;
    const int vbase = local * TPB;

    // ---- stage all 28 class-slabs via global_load_lds (no VGPR results) ----
    // wave w stages slabs [7w, 7w+7); one inst = 64 lanes x 16 B = 1 KB = 1 slab
    const float* Sb = S + (size_t)b * NC * VOL + vbase;
    const float* Tb = T + (size_t)b * NC * VOL + vbase;
#pragma unroll
    for (int j = 0; j < 7; ++j) {
        const int st = wid * 7 + j;            // 0..27
        const float* g = (st < NC) ? (Sb + st * VOL) : (Tb + (st - NC) * VOL);
        __builtin_amdgcn_global_load_lds((as1_cvoid*)(g + lane * 4),
                                         (as3_void*)(&smem[st * TPB]),
                                         16, 0, 0);
    }

    // ---- labels / boundary mask for this thread's voxel (overlaps staging) ----
    const int v = vbase + tid;
    const int d = v % DIM;
    const int w = (v / DIM) % DIM;
    const int h = v / (DIM * DIM);
    const int* lab = L + b * VOL + (h * DIM + w) * DIM + d;   // center voxel
    unsigned mask = 0;
#pragma unroll
    for (int dh = -1; dh <= 1; ++dh) {
#pragma unroll
        for (int dw = -1; dw <= 1; ++dw) {
            const int h2 = h + dh, w2 = w + dw;
            if (((unsigned)h2 < DIM) & ((unsigned)w2 < DIM)) {
                const int* p = lab + (dh * DIM + dw) * DIM;
                if (d > 0)       mask |= 1u << p[-1];
                if (d < DIM - 1) mask |= 1u << p[1];
                if (!(dh == 0 && dw == 0)) mask |= 1u << p[0];
            }
        }
    }
    {
        // conv == 26 (all 26 neighbors exist and share one label) -> clear bit
        const int nh = 3 - (h == 0) - (h == DIM - 1);
        const int nw = 3 - (w == 0) - (w == DIM - 1);
        const int nd = 3 - (d == 0) - (d == DIM - 1);
        if (nh * nw * nd - 1 == 26 && __popc(mask) == 1) mask = 0;
    }

    __syncthreads();   // compiler emits vmcnt(0) drain -> all slabs resident

    // ---- consume from LDS: online exp sums over 14 classes ----
    // kl = A/ET + log(ES) - log(ET)  (exact algebra; logits ~N(0,1), exp safe)
    float ES = 0.f, ET = 0.f, A = 0.f;
#pragma unroll
    for (int c = 0; c < NC; ++c) {
        const float s = smem[c * TPB + tid];
        const float t = smem[(NC + c) * TPB + tid];
        ES += __expf(s);
        const float et = __expf(t);
        ET += et;
        A += et * (t - s);
    }
    const float kl = A / ET + __logf(ES) - __logf(ET);

    // ---- per-class block reduction: butterfly for sums, ballot for counts ----
#pragma unroll
    for (int k = 0; k < NC; ++k) {
        const bool on = (mask >> k) & 1u;
        float sv = on ? kl : 0.f;
#pragma unroll
        for (int off = 32; off; off >>= 1) sv += __shfl_xor(sv, off);
        const unsigned long long bal = __ballot(on);
        if (lane == 0) {
            lds_sum[wid][k] = sv;
            lds_cnt[wid][k] = (float)__popcll(bal);
        }
    }
    __syncthreads();
    if (tid < 2 * NC) {
        const int k = (tid < NC) ? tid : tid - NC;
        float r;
        if (tid < NC) r = lds_sum[0][k] + lds_sum[1][k] + lds_sum[2][k] + lds_sum[3][k];
        else          r = lds_cnt[0][k] + lds_cnt[1][k] + lds_cnt[2][k] + lds_cnt[3][k];
        const int row = (tid < NC) ? (b * NC + k) : (2 * NC + b * NC + k);
        partials[(size_t)row * NBPB + local] = r;
    }
}

// 56 blocks x 256 threads: reduce one 3456-wide partials row each
__global__ __launch_bounds__(256) void bkd_reduce(const float* __restrict__ partials,
                                                  float* __restrict__ res) {
    const int row = blockIdx.x;
    const int tid = threadIdx.x;
    const int lane = tid & 63, wid = tid >> 6;
    __shared__ float r4[4];
    float acc = 0.f;
    for (int i = tid; i < NBPB; i += 256) acc += partials[(size_t)row * NBPB + i];
#pragma unroll
    for (int off = 32; off; off >>= 1) acc += __shfl_xor(acc, off);
    if (lane == 0) r4[wid] = acc;
    __syncthreads();
    if (tid == 0) res[row] = r4[0] + r4[1] + r4[2] + r4[3];
}

// single wave: combine 28 (sum,count) pairs into the scalar loss
__global__ __launch_bounds__(64) void bkd_last(const float* __restrict__ res,
                                               float* __restrict__ out) {
    const int j = threadIdx.x;
    float per = 0.f, valid = 0.f;
    if (j < 2 * NC) {
        const float nb = res[2 * NC + j];
        if (nb > 0.f) {
            per = res[j] / (NC * nb);
            valid = 1.f;
        }
    }
#pragma unroll
    for (int off = 32; off; off >>= 1) {
        per += __shfl_xor(per, off);
        valid += __shfl_xor(valid, off);
    }
    if (j == 0) out[0] = (valid > 0.f) ? (per / valid) : 0.f;
}

extern "C" void kernel_launch(void* const* d_in, const int* in_sizes, int n_in,
                              void* d_out, int out_size, void* d_ws, size_t ws_size,
                              hipStream_t stream) {
    const float* S = (const float*)d_in[0];
    const float* T = (const float*)d_in[1];
    const int* L = (const int*)d_in[2];
    float* out = (float*)d_out;
    float* partials = (float*)d_ws;            // 56 rows x 3456 floats = 774,144 B
    float* res = partials + (size_t)4 * NC * NBPB;  // 56 floats after partials

    bkd_main<<<dim3(2 * NBPB), dim3(TPB), 0, stream>>>(S, T, L, partials);
    bkd_reduce<<<dim3(4 * NC), dim3(256), 0, stream>>>(partials, res);
    bkd_last<<<dim3(1), dim3(64), 0, stream>>>(res, out);
}

// Round 9
// 57.998 us; speedup vs baseline: 1.6305x; 1.6305x over previous
//
#include <hip/hip_runtime.h>

#define NC 14
#define DIM 96
#define VOL (96 * 96 * 96)   // 884736
#define VPT 4                 // voxels per thread
#define TPB 256
#define VPB (VPT * TPB)       // 1024
#define NBPB (VOL / VPB)      // 864 blocks per batch (exact)

typedef float f32x4 __attribute__((ext_vector_type(4)));

__global__ __launch_bounds__(256, 2) void bkd_main(const float* __restrict__ S,
                                                   const float* __restrict__ T,
                                                   const int* __restrict__ L,
                                                   float* __restrict__ partials) {
    const int b = blockIdx.x / NBPB;
    const int local = blockIdx.x % NBPB;
    const int tid = threadIdx.x;
    const int v0 = local * VPB + tid * VPT;   // multiple of 4
    const int d0 = v0 % DIM;
    const int w = (v0 / DIM) % DIM;
    const int h = v0 / (DIM * DIM);

    const float* Sb = S + (size_t)b * NC * VOL + v0;
    const float* Tb = T + (size_t)b * NC * VOL + v0;
    const int* lab = L + b * VOL;

    // ---------------- issue LABEL loads first (cached; 27x reuse) -------------
    const bool has_lo = (d0 > 0);
    const bool has_hi = (d0 + VPT < DIM);
    int4 q[9];
    int plo[9], phi[9];
    bool cvalid[9];
#pragma unroll
    for (int dh = -1; dh <= 1; ++dh) {
#pragma unroll
        for (int dw = -1; dw <= 1; ++dw) {
            const int ci = (dh + 1) * 3 + (dw + 1);
            const int h2 = h + dh, w2 = w + dw;
            const bool ok = ((unsigned)h2 < DIM) & ((unsigned)w2 < DIM);
            cvalid[ci] = ok;
            const int* p = lab + (h2 * DIM + w2) * DIM + d0;
            if (ok) {
                q[ci] = *(const int4*)p;                       // labels d0..d0+3
                plo[ci] = has_lo ? p[-1] : 0;
                phi[ci] = has_hi ? p[4] : 0;
            }
        }
    }

    // ------- issue ALL 28 class float4 loads, NON-TEMPORAL (zero reuse) -------
    f32x4 sv[NC], tv[NC];
#pragma unroll
    for (int c = 0; c < NC; ++c) {
        sv[c] = __builtin_nontemporal_load((const f32x4*)(Sb + c * VOL));
        tv[c] = __builtin_nontemporal_load((const f32x4*)(Tb + c * VOL));
    }

    // Fence: keep all loads issued back-to-back before any consumption.
    __builtin_amdgcn_sched_barrier(0);

    // ---------------- boundary masks (VALU under class-load latency) ----------
    unsigned vmask[VPT] = {0u, 0u, 0u, 0u};
#pragma unroll
    for (int ci = 0; ci < 9; ++ci) {
        if (cvalid[ci]) {
            const unsigned m1 = 1u << q[ci].x;
            const unsigned m2 = 1u << q[ci].y;
            const unsigned m3 = 1u << q[ci].z;
            const unsigned m4 = 1u << q[ci].w;
            const unsigned m0 = has_lo ? (1u << plo[ci]) : 0u;
            const unsigned m5 = has_hi ? (1u << phi[ci]) : 0u;
            const bool isC = (ci == 4);                        // compile-time
            vmask[0] |= m0 | m2 | (isC ? 0u : m1);
            vmask[1] |= m1 | m3 | (isC ? 0u : m2);
            vmask[2] |= m2 | m4 | (isC ? 0u : m3);
            vmask[3] |= m3 | m5 | (isC ? 0u : m4);
        }
    }
    {
        // conv == 26 (all 26 neighbors exist, single label) -> clear that bit
        const int nh = 3 - (h == 0) - (h == DIM - 1);
        const int nw = 3 - (w == 0) - (w == DIM - 1);
        const int ncols = nh * nw;
        const int nn0 = ncols * (has_lo ? 3 : 2) - 1;
        const int nn12 = ncols * 3 - 1;
        const int nn3 = ncols * (has_hi ? 3 : 2) - 1;
        if (nn0 == 26 && __popc(vmask[0]) == 1) vmask[0] = 0u;
        if (nn12 == 26 && __popc(vmask[1]) == 1) vmask[1] = 0u;
        if (nn12 == 26 && __popc(vmask[2]) == 1) vmask[2] = 0u;
        if (nn3 == 26 && __popc(vmask[3]) == 1) vmask[3] = 0u;
    }

    // ---------------- online exp sums, consumed in issue order ----------------
    // kl_i = A_i/ET_i + log(ES_i) - log(ET_i)   (exact algebra; logits ~N(0,1))
    float ES[VPT] = {0.f, 0.f, 0.f, 0.f};
    float ET[VPT] = {0.f, 0.f, 0.f, 0.f};
    float Aa[VPT] = {0.f, 0.f, 0.f, 0.f};
#pragma unroll
    for (int c = 0; c < NC; ++c) {
        const f32x4 s = sv[c];
        const f32x4 t = tv[c];
#pragma unroll
        for (int i = 0; i < VPT; ++i) {
            const float es = __expf(s[i]), et = __expf(t[i]);
            ES[i] += es; ET[i] += et; Aa[i] += et * (t[i] - s[i]);
        }
    }

    float kl[VPT];
#pragma unroll
    for (int i = 0; i < VPT; ++i) {
        kl[i] = Aa[i] / ET[i] + __logf(ES[i]) - __logf(ET[i]);
    }

    // ---------------- masked per-class accumulation ----------------
    float acc_sum[NC];
    float acc_cnt[NC];
#pragma unroll
    for (int k = 0; k < NC; ++k) { acc_sum[k] = 0.f; acc_cnt[k] = 0.f; }
#pragma unroll
    for (int i = 0; i < VPT; ++i) {
#pragma unroll
        for (int k = 0; k < NC; ++k) {
            if (vmask[i] & (1u << k)) { acc_sum[k] += kl[i]; acc_cnt[k] += 1.f; }
        }
    }

    // ---------------- block reduction: wave shuffle, then LDS combine ---------
    __shared__ float lds[4][2 * NC];
    const int lane = tid & 63, wid = tid >> 6;
#pragma unroll
    for (int k = 0; k < NC; ++k) {
        float svv = acc_sum[k], cvv = acc_cnt[k];
#pragma unroll
        for (int off = 32; off; off >>= 1) {
            svv += __shfl_xor(svv, off);
            cvv += __shfl_xor(cvv, off);
        }
        if (lane == 0) { lds[wid][k] = svv; lds[wid][NC + k] = cvv; }
    }
    __syncthreads();
    if (tid < 2 * NC) {
        const float r = lds[0][tid] + lds[1][tid] + lds[2][tid] + lds[3][tid];
        const int k = (tid < NC) ? tid : (tid - NC);
        const int p = (tid < NC) ? (b * NC + k) : (2 * NC + b * NC + k);
        partials[p * NBPB + local] = r;
    }
}

// 56 blocks x 64 threads: reduce one partials row each
__global__ __launch_bounds__(64) void bkd_reduce(const float* __restrict__ partials,
                                                 float* __restrict__ res) {
    const int p = blockIdx.x;
    const int lane = threadIdx.x;
    float acc = 0.f;
    for (int i = lane; i < NBPB; i += 64) acc += partials[p * NBPB + i];
#pragma unroll
    for (int off = 32; off; off >>= 1) acc += __shfl_xor(acc, off);
    if (lane == 0) res[p] = acc;
}

// single wave: combine 28 (sum,count) pairs into the scalar loss
__global__ __launch_bounds__(64) void bkd_last(const float* __restrict__ res,
                                               float* __restrict__ out) {
    const int j = threadIdx.x;
    float per = 0.f, valid = 0.f;
    if (j < 2 * NC) {
        const float nb = res[2 * NC + j];
        if (nb > 0.f) {
            per = res[j] / (NC * nb);
            valid = 1.f;
        }
    }
#pragma unroll
    for (int off = 32; off; off >>= 1) {
        per += __shfl_xor(per, off);
        valid += __shfl_xor(valid, off);
    }
    if (j == 0) out[0] = (valid > 0.f) ? (per / valid) : 0.f;
}

extern "C" void kernel_launch(void* const* d_in, const int* in_sizes, int n_in,
                              void* d_out, int out_size, void* d_ws, size_t ws_size,
                              hipStream_t stream) {
    const float* S = (const float*)d_in[0];
    const float* T = (const float*)d_in[1];
    const int* L = (const int*)d_in[2];
    float* out = (float*)d_out;
    float* partials = (float*)d_ws;                 // 56 * 864 floats = 193,536 B
    float* res = partials + 2 * NC * 2 * NBPB;      // 56 floats after partials

    bkd_main<<<dim3(2 * NBPB), dim3(TPB), 0, stream>>>(S, T, L, partials);
    bkd_reduce<<<dim3(4 * NC), dim3(64), 0, stream>>>(partials, res);
    bkd_last<<<dim3(1), dim3(64), 0, stream>>>(res, out);
}

// Round 10
// 53.255 us; speedup vs baseline: 1.7757x; 1.0891x over previous
//
#include <hip/hip_runtime.h>

#define NC 14
#define DIM 96
#define VOL (96 * 96 * 96)   // 884736
#define VPT 4                 // voxels per thread
#define TPB 256
#define VPB (VPT * TPB)       // 1024
#define NBPB (VOL / VPB)      // 864 blocks per batch (exact)
#define NT_SPLIT 7            // classes 0..6 non-temporal (HBM path), 7..13 cached (L3 path)

typedef float f32x4 __attribute__((ext_vector_type(4)));

__global__ __launch_bounds__(256, 2) void bkd_main(const float* __restrict__ S,
                                                   const float* __restrict__ T,
                                                   const int* __restrict__ L,
                                                   float* __restrict__ partials) {
    const int b = blockIdx.x / NBPB;
    const int local = blockIdx.x % NBPB;
    const int tid = threadIdx.x;
    const int v0 = local * VPB + tid * VPT;   // multiple of 4
    const int d0 = v0 % DIM;
    const int w = (v0 / DIM) % DIM;
    const int h = v0 / (DIM * DIM);

    const float* Sb = S + (size_t)b * NC * VOL + v0;
    const float* Tb = T + (size_t)b * NC * VOL + v0;
    const int* lab = L + b * VOL;

    // ---------------- issue LABEL loads first (cached; 27x reuse) -------------
    const bool has_lo = (d0 > 0);
    const bool has_hi = (d0 + VPT < DIM);
    int4 q[9];
    int plo[9], phi[9];
    bool cvalid[9];
#pragma unroll
    for (int dh = -1; dh <= 1; ++dh) {
#pragma unroll
        for (int dw = -1; dw <= 1; ++dw) {
            const int ci = (dh + 1) * 3 + (dw + 1);
            const int h2 = h + dh, w2 = w + dw;
            const bool ok = ((unsigned)h2 < DIM) & ((unsigned)w2 < DIM);
            cvalid[ci] = ok;
            const int* p = lab + (h2 * DIM + w2) * DIM + d0;
            if (ok) {
                q[ci] = *(const int4*)p;                       // labels d0..d0+3
                plo[ci] = has_lo ? p[-1] : 0;
                phi[ci] = has_hi ? p[4] : 0;
            }
        }
    }

    // ---- issue ALL 28 class float4 loads; split across L3 and HBM paths ------
    f32x4 sv[NC], tv[NC];
#pragma unroll
    for (int c = 0; c < NC; ++c) {
        if (c < NT_SPLIT) {
            sv[c] = __builtin_nontemporal_load((const f32x4*)(Sb + c * VOL));
            tv[c] = __builtin_nontemporal_load((const f32x4*)(Tb + c * VOL));
        } else {
            sv[c] = *(const f32x4*)(Sb + c * VOL);
            tv[c] = *(const f32x4*)(Tb + c * VOL);
        }
    }

    // Fence: keep all loads issued back-to-back before any consumption.
    __builtin_amdgcn_sched_barrier(0);

    // ---------------- boundary masks (VALU under class-load latency) ----------
    unsigned vmask[VPT] = {0u, 0u, 0u, 0u};
#pragma unroll
    for (int ci = 0; ci < 9; ++ci) {
        if (cvalid[ci]) {
            const unsigned m1 = 1u << q[ci].x;
            const unsigned m2 = 1u << q[ci].y;
            const unsigned m3 = 1u << q[ci].z;
            const unsigned m4 = 1u << q[ci].w;
            const unsigned m0 = has_lo ? (1u << plo[ci]) : 0u;
            const unsigned m5 = has_hi ? (1u << phi[ci]) : 0u;
            const bool isC = (ci == 4);                        // compile-time
            vmask[0] |= m0 | m2 | (isC ? 0u : m1);
            vmask[1] |= m1 | m3 | (isC ? 0u : m2);
            vmask[2] |= m2 | m4 | (isC ? 0u : m3);
            vmask[3] |= m3 | m5 | (isC ? 0u : m4);
        }
    }
    {
        // conv == 26 (all 26 neighbors exist, single label) -> clear that bit
        const int nh = 3 - (h == 0) - (h == DIM - 1);
        const int nw = 3 - (w == 0) - (w == DIM - 1);
        const int ncols = nh * nw;
        const int nn0 = ncols * (has_lo ? 3 : 2) - 1;
        const int nn12 = ncols * 3 - 1;
        const int nn3 = ncols * (has_hi ? 3 : 2) - 1;
        if (nn0 == 26 && __popc(vmask[0]) == 1) vmask[0] = 0u;
        if (nn12 == 26 && __popc(vmask[1]) == 1) vmask[1] = 0u;
        if (nn12 == 26 && __popc(vmask[2]) == 1) vmask[2] = 0u;
        if (nn3 == 26 && __popc(vmask[3]) == 1) vmask[3] = 0u;
    }

    // ---------------- online exp sums, consumed in issue order ----------------
    // kl_i = A_i/ET_i + log(ES_i) - log(ET_i)   (exact algebra; logits ~N(0,1))
    float ES[VPT] = {0.f, 0.f, 0.f, 0.f};
    float ET[VPT] = {0.f, 0.f, 0.f, 0.f};
    float Aa[VPT] = {0.f, 0.f, 0.f, 0.f};
#pragma unroll
    for (int c = 0; c < NC; ++c) {
        const f32x4 s = sv[c];
        const f32x4 t = tv[c];
#pragma unroll
        for (int i = 0; i < VPT; ++i) {
            const float es = __expf(s[i]), et = __expf(t[i]);
            ES[i] += es; ET[i] += et; Aa[i] += et * (t[i] - s[i]);
        }
    }

    float kl[VPT];
#pragma unroll
    for (int i = 0; i < VPT; ++i) {
        kl[i] = Aa[i] / ET[i] + __logf(ES[i]) - __logf(ET[i]);
    }

    // ---------------- masked per-class accumulation ----------------
    float acc_sum[NC];
    float acc_cnt[NC];
#pragma unroll
    for (int k = 0; k < NC; ++k) { acc_sum[k] = 0.f; acc_cnt[k] = 0.f; }
#pragma unroll
    for (int i = 0; i < VPT; ++i) {
#pragma unroll
        for (int k = 0; k < NC; ++k) {
            if (vmask[i] & (1u << k)) { acc_sum[k] += kl[i]; acc_cnt[k] += 1.f; }
        }
    }

    // ---------------- block reduction: wave shuffle, then LDS combine ---------
    __shared__ float lds[4][2 * NC];
    const int lane = tid & 63, wid = tid >> 6;
#pragma unroll
    for (int k = 0; k < NC; ++k) {
        float svv = acc_sum[k], cvv = acc_cnt[k];
#pragma unroll
        for (int off = 32; off; off >>= 1) {
            svv += __shfl_xor(svv, off);
            cvv += __shfl_xor(cvv, off);
        }
        if (lane == 0) { lds[wid][k] = svv; lds[wid][NC + k] = cvv; }
    }
    __syncthreads();
    if (tid < 2 * NC) {
        const float r = lds[0][tid] + lds[1][tid] + lds[2][tid] + lds[3][tid];
        const int k = (tid < NC) ? tid : (tid - NC);
        const int p = (tid < NC) ? (b * NC + k) : (2 * NC + b * NC + k);
        partials[p * NBPB + local] = r;
    }
}

// 56 blocks x 64 threads: reduce one partials row each
__global__ __launch_bounds__(64) void bkd_reduce(const float* __restrict__ partials,
                                                 float* __restrict__ res) {
    const int p = blockIdx.x;
    const int lane = threadIdx.x;
    float acc = 0.f;
    for (int i = lane; i < NBPB; i += 64) acc += partials[p * NBPB + i];
#pragma unroll
    for (int off = 32; off; off >>= 1) acc += __shfl_xor(acc, off);
    if (lane == 0) res[p] = acc;
}

// single wave: combine 28 (sum,count) pairs into the scalar loss
__global__ __launch_bounds__(64) void bkd_last(const float* __restrict__ res,
                                               float* __restrict__ out) {
    const int j = threadIdx.x;
    float per = 0.f, valid = 0.f;
    if (j < 2 * NC) {
        const float nb = res[2 * NC + j];
        if (nb > 0.f) {
            per = res[j] / (NC * nb);
            valid = 1.f;
        }
    }
#pragma unroll
    for (int off = 32; off; off >>= 1) {
        per += __shfl_xor(per, off);
        valid += __shfl_xor(valid, off);
    }
    if (j == 0) out[0] = (valid > 0.f) ? (per / valid) : 0.f;
}

extern "C" void kernel_launch(void* const* d_in, const int* in_sizes, int n_in,
                              void* d_out, int out_size, void* d_ws, size_t ws_size,
                              hipStream_t stream) {
    const float* S = (const float*)d_in[0];
    const float* T = (const float*)d_in[1];
    const int* L = (const int*)d_in[2];
    float* out = (float*)d_out;
    float* partials = (float*)d_ws;                 // 56 * 864 floats = 193,536 B
    float* res = partials + 2 * NC * 2 * NBPB;      // 56 floats after partials

    bkd_main<<<dim3(2 * NBPB), dim3(TPB), 0, stream>>>(S, T, L, partials);
    bkd_reduce<<<dim3(4 * NC), dim3(64), 0, stream>>>(partials, res);
    bkd_last<<<dim3(1), dim3(64), 0, stream>>>(res, out);
}